// Round 1
// baseline (520.061 us; speedup 1.0000x reference)
//
#include <hip/hip_runtime.h>

// MMoE: B=16384, D=1024, E=8, H=512, T=256, TASKS=3
// R2: 701 us (gates stride-8 reads). R3: 593 us (coalesced gates).
// R4: 521 us (XOR-swizzled GEMM LDS -> bank conflicts 2.5e7 -> 0).
// R5: 498 us fuse tail; 10 launches.
// R6: 256x256 8-phase counted-vmcnt GEMM (T3+T4+T5 on top of T2) for the two
//     expert GEMMs. m97 2-barrier structure ceiling ~900 TF -> 8-phase
//     template ~1550 TF. Schedule (race-free by construction):
//       tile t (buf cur), phase p reads A rows {32p..32p+31} per wave-group
//       and (p==0) all B; staging per phase overwrites only regions consumed
//       in phases < p:  p0: A-h2(t+1)->cur^1 | p1: B-h1(t+2)->cur |
//       p2: A-h1(t+2)->cur | p3: B-h2(t+2)->cur.  A halves interleaved
//       {0-63,128-191}/{64-127,192-255}; B consumed wholly in p0.
//       vmcnt(6)+barrier once per tile boundary (3 half-tiles in flight).
//
// Workspace: fixed 48,594,944 B + Bc*19456 B chunk buffers (Bc adapts).

#define BM 128
#define BN 128
#define BK 64

typedef __attribute__((ext_vector_type(8))) short short8;
typedef __attribute__((ext_vector_type(4))) float floatx4;
typedef __attribute__((ext_vector_type(4))) unsigned short ushortx4;
typedef __attribute__((ext_vector_type(8))) unsigned short ushortx8;

__device__ __forceinline__ unsigned short f32_to_bf16(float f) {
  unsigned int u = __float_as_uint(f);
  u += 0x7fffu + ((u >> 16) & 1u);   // round-to-nearest-even (no NaNs in this net)
  return (unsigned short)(u >> 16);
}
__device__ __forceinline__ float bf16_to_f32(unsigned short h) {
  return __uint_as_float(((unsigned int)h) << 16);
}

__device__ __forceinline__ void async_cp16(const void* g, void* lds) {
  __builtin_amdgcn_global_load_lds(
      (const __attribute__((address_space(1))) void*)g,
      (__attribute__((address_space(3))) void*)lds, 16, 0, 0);
}

// ---------------- all weight prep in one kernel ----------------
// grid (16,32,20), block (32,8):
//   z 0..7  : We1 slice z  [1024][512] -> W1T  [512][1024] bf16
//   z 8..15 : We2 slice    [512][512]  -> W2T  [512][512]  bf16 (y<16)
//   z 16..18: Wt1 slice    [512][256]  -> Wt1T [256][512]  bf16 (x<8,y<16)
//   z 19    : Wg [3][1024][8] -> WgT [3][8][1024] fp32      (x<16,y<6)
__device__ __forceinline__ void transpose_slice(
    const float* __restrict__ in, unsigned short* __restrict__ out,
    int K, int N, float (*tile)[33]) {
  int n0 = blockIdx.x * 32, k0 = blockIdx.y * 32;
  for (int i = threadIdx.y; i < 32; i += 8)
    tile[i][threadIdx.x] = in[(size_t)(k0 + i) * N + n0 + threadIdx.x];
  __syncthreads();
  for (int i = threadIdx.y; i < 32; i += 8)
    out[(size_t)(n0 + i) * K + k0 + threadIdx.x] = f32_to_bf16(tile[threadIdx.x][i]);
}

__global__ void prep_kernel(const float* __restrict__ We1, const float* __restrict__ We2,
                            const float* __restrict__ Wt1, const float* __restrict__ Wg,
                            unsigned short* __restrict__ W1T, unsigned short* __restrict__ W2T,
                            unsigned short* __restrict__ Wt1T, float* __restrict__ WgT) {
  __shared__ float tile[32][33];
  int z = blockIdx.z;
  if (z < 8) {
    transpose_slice(We1 + (size_t)z * 524288, W1T + (size_t)z * 524288, 1024, 512, tile);
  } else if (z < 16) {
    if (blockIdx.y < 16)
      transpose_slice(We2 + (size_t)(z - 8) * 262144, W2T + (size_t)(z - 8) * 262144, 512, 512, tile);
  } else if (z < 19) {
    if (blockIdx.x < 8 && blockIdx.y < 16)
      transpose_slice(Wt1 + (size_t)(z - 16) * 131072, Wt1T + (size_t)(z - 16) * 131072, 512, 256, tile);
  } else {
    if (blockIdx.x < 16 && blockIdx.y < 6) {
      int idx = (blockIdx.y * 16 + blockIdx.x) * 256 + threadIdx.y * 32 + threadIdx.x;
      int t = idx >> 13, r = idx & 8191, e = r >> 10, d = r & 1023;
      WgT[idx] = Wg[t * 8192 + d * 8 + e];
    }
  }
}

// ---------------- gates + x->bf16 (fused; reads x once) ----------------
// WgT: [3][8][1024] fp32. One wave per batch row.
__global__ __launch_bounds__(256) void gates_cvt_kernel(
    const float* __restrict__ x, const float* __restrict__ WgT,
    const float* __restrict__ bg, float* __restrict__ gout,
    unsigned short* __restrict__ xb) {
  int wave = threadIdx.x >> 6, lane = threadIdx.x & 63;
  int b = blockIdx.x * 4 + wave;
  const float* xr = x + (size_t)b * 1024;
  float xv[16];
#pragma unroll
  for (int j = 0; j < 16; j++) xv[j] = xr[lane + 64 * j];
  unsigned short* xbr = xb + (size_t)b * 1024;
#pragma unroll
  for (int j = 0; j < 16; j++) xbr[lane + 64 * j] = f32_to_bf16(xv[j]);
  float mylogit = 0.f;
#pragma unroll
  for (int te = 0; te < 24; te++) {
    const float* w = WgT + te * 1024;
    float a = 0.f;
#pragma unroll
    for (int j = 0; j < 16; j++) a += xv[j] * w[lane + 64 * j];
#pragma unroll
    for (int off = 32; off > 0; off >>= 1) a += __shfl_xor(a, off, 64);
    if (lane == te) mylogit = a;   // compile-time te -> cndmask, no LDS
  }
  if (lane < 24) {   // groups of 8 (tasks) are 8-lane aligned; xor 4/2/1 stays in-group
    int t = lane >> 3, e = lane & 7;
    float logit = mylogit + bg[lane];
    float m = logit;
    m = fmaxf(m, __shfl_xor(m, 4, 64));
    m = fmaxf(m, __shfl_xor(m, 2, 64));
    m = fmaxf(m, __shfl_xor(m, 1, 64));
    float ex = __expf(logit - m);
    float s = ex;
    s += __shfl_xor(s, 4, 64);
    s += __shfl_xor(s, 2, 64);
    s += __shfl_xor(s, 1, 64);
    gout[(size_t)t * 131072 + (size_t)b * 8 + e] = ex / s;
  }
}

// ---------------- m97-style bf16 GEMM (fallback for small Bc) ----------------
// C = relu(A * B^T + bias), bf16 out. LDS XOR-swizzled.
__global__ __launch_bounds__(256) void gemm_bt_relu(
    const unsigned short* __restrict__ Abase, long aOffZ, int lda,
    const unsigned short* __restrict__ Bbase, long bOffZ,
    const float* __restrict__ biasBase, int biasOffZ,
    unsigned short* __restrict__ Cbase, long cOffZ, int ldc,
    int K) {
  __shared__ __align__(16) unsigned short As[BM * BK];
  __shared__ __align__(16) unsigned short Bs[BN * BK];
  const int tid = threadIdx.x;
  const int z = blockIdx.z;
  const unsigned short* A = Abase + (size_t)aOffZ * z + (size_t)blockIdx.x * BM * lda;
  const unsigned short* Bt = Bbase + (size_t)bOffZ * z + (size_t)blockIdx.y * BN * K;
  const float* bias = biasBase + (size_t)biasOffZ * z + blockIdx.y * BN;
  unsigned short* C = Cbase + (size_t)cOffZ * z + (size_t)blockIdx.x * BM * ldc + blockIdx.y * BN;

  const int wave = tid >> 6, lane = tid & 63;
  const int wm = (wave >> 1) * 64, wn = (wave & 1) * 64;
  const int lm = lane & 15, lq = lane >> 4;
  const int sw = lm & 7;            // read-side swizzle key (= row & 7)

  floatx4 acc[4][4] = {};

  const int sr = tid >> 3;                               // staging row 0..31
  const int sc = (((tid & 7) ^ (sr & 7)) << 3);          // swizzled source col (elements)

  for (int kt = 0; kt < K; kt += BK) {
#pragma unroll
    for (int i = 0; i < 4; i++)
      async_cp16(A + (size_t)(sr + 32 * i) * lda + kt + sc,
                 (char*)As + i * 4096 + tid * 16);
#pragma unroll
    for (int i = 0; i < 4; i++)
      async_cp16(Bt + (size_t)(sr + 32 * i) * K + kt + sc,
                 (char*)Bs + i * 4096 + tid * 16);
    __syncthreads();   // drains vmcnt -> staged tiles visible
#pragma unroll
    for (int ks = 0; ks < 2; ks++) {
      short8 af[4], bf[4];
      const int ch = ((ks * 4 + lq) ^ sw) << 3;          // swizzled chunk (elements)
#pragma unroll
      for (int i = 0; i < 4; i++)
        af[i] = *(const short8*)(As + (wm + 16 * i + lm) * BK + ch);
#pragma unroll
      for (int j = 0; j < 4; j++)
        bf[j] = *(const short8*)(Bs + (wn + 16 * j + lm) * BK + ch);
#pragma unroll
      for (int i = 0; i < 4; i++)
#pragma unroll
        for (int j = 0; j < 4; j++)
          acc[i][j] = __builtin_amdgcn_mfma_f32_16x16x32_bf16(af[i], bf[j], acc[i][j], 0, 0, 0);
    }
    __syncthreads();   // protect LDS reuse next iter
  }

#pragma unroll
  for (int i = 0; i < 4; i++) {
    const int row = wm + 16 * i + lq * 4;
#pragma unroll
    for (int j = 0; j < 4; j++) {
      const int col = wn + 16 * j + lm;
      const float bv = bias[col];
#pragma unroll
      for (int v = 0; v < 4; v++) {
        float val = fmaxf(acc[i][j][v] + bv, 0.0f);
        C[(size_t)(row + v) * ldc + col] = f32_to_bf16(val);
      }
    }
  }
}

// ---------------- 256x256 8-phase counted-vmcnt GEMM ----------------
// C = relu(A * B^T + bias), bf16 out. 512 threads = 8 waves (2M x 4N),
// per-wave 128x64 output. LDS 128 KiB: As[2][256][64] + Bs[2][256][64].
// Same chunk-XOR swizzle as gemm_bt_relu (slot (r,c') holds chunk c'^(r&7)).

// stage half 'half' of A for tile tt into buffer buf (2 global_load_lds).
// half 0 -> rows {0..63, 128..191}; half 1 -> rows {64..127, 192..255}
#define STAGE_A256(buf, half, tt) do {                                       \
    const int kt_ = ((tt) < NT ? (tt) : 0) << 6;                             \
    _Pragma("unroll") for (int g_ = 0; g_ < 2; ++g_) {                       \
      const int rb_ = ((half) + 2 * g_) * 64;                                \
      async_cp16(A + (size_t)(rb_ + sr) * lda + kt_ + sc,                    \
                 (char*)As + (buf) * 32768 + rb_ * 128 + tid * 16);          \
    } } while (0)

// stage half 'half' of B (contiguous 128 rows) for tile tt into buffer buf.
#define STAGE_B256(buf, half, tt) do {                                       \
    const int kt_ = ((tt) < NT ? (tt) : 0) << 6;                             \
    _Pragma("unroll") for (int g_ = 0; g_ < 2; ++g_) {                       \
      const int rb_ = (half) * 128 + g_ * 64;                                \
      async_cp16(Bt + (size_t)(rb_ + sr) * K + kt_ + sc,                     \
                 (char*)Bs + (buf) * 32768 + rb_ * 128 + tid * 16);          \
    } } while (0)

#define DS_A256(mi, ks)                                                      \
  (*(const short8*)(As + cur * 16384 + (wm + 16 * (mi) + lm) * 64 +          \
                    ((((ks) * 4 + lq) ^ sw) << 3)))
#define DS_B256(nj, ks)                                                      \
  (*(const short8*)(Bs + cur * 16384 + (wn + 16 * (nj) + lm) * 64 +          \
                    ((((ks) * 4 + lq) ^ sw) << 3)))

// phase p: ds-reads (A frags 2p,2p+1; +all B frags at p==0), issue 1 half-tile
// stage, barrier, lgkmcnt(0)+sched_barrier, setprio'd 16 MFMA, [vmcnt(6)],
// barrier. p must be a literal (acc indexing stays compile-time).
#define PHASE256(p, STAGE_STMT, ENDWAIT) do {                                \
    short8 af[2][2];                                                         \
    af[0][0] = DS_A256(2 * (p) + 0, 0); af[0][1] = DS_A256(2 * (p) + 0, 1);  \
    af[1][0] = DS_A256(2 * (p) + 1, 0); af[1][1] = DS_A256(2 * (p) + 1, 1);  \
    if ((p) == 0) {                                                          \
      _Pragma("unroll") for (int nj = 0; nj < 4; ++nj) {                     \
        bf[nj][0] = DS_B256(nj, 0); bf[nj][1] = DS_B256(nj, 1);              \
      }                                                                      \
    }                                                                        \
    STAGE_STMT;                                                              \
    __builtin_amdgcn_s_barrier();                                            \
    asm volatile("s_waitcnt lgkmcnt(0)" ::: "memory");                       \
    __builtin_amdgcn_sched_barrier(0);                                       \
    __builtin_amdgcn_s_setprio(1);                                           \
    _Pragma("unroll") for (int d_ = 0; d_ < 2; ++d_)                         \
      _Pragma("unroll") for (int nj = 0; nj < 4; ++nj)                       \
        _Pragma("unroll") for (int ks = 0; ks < 2; ++ks)                     \
          acc[2 * (p) + d_][nj] = __builtin_amdgcn_mfma_f32_16x16x32_bf16(   \
              af[d_][ks], bf[nj][ks], acc[2 * (p) + d_][nj], 0, 0, 0);       \
    __builtin_amdgcn_s_setprio(0);                                           \
    if (ENDWAIT) asm volatile("s_waitcnt vmcnt(6)" ::: "memory");            \
    __builtin_amdgcn_s_barrier();                                            \
  } while (0)

__global__ __launch_bounds__(512) void gemm256_bt_relu(
    const unsigned short* __restrict__ Abase, long aOffZ, int lda,
    const unsigned short* __restrict__ Bbase, long bOffZ,
    const float* __restrict__ biasBase, int biasOffZ,
    unsigned short* __restrict__ Cbase, long cOffZ, int ldc,
    int K) {
  __shared__ __align__(16) unsigned short As[2 * 256 * 64];   // 64 KB
  __shared__ __align__(16) unsigned short Bs[2 * 256 * 64];   // 64 KB
  const int tid = threadIdx.x;
  const int z = blockIdx.z;
  const unsigned short* A = Abase + (size_t)aOffZ * z + (size_t)blockIdx.x * 256 * lda;
  const unsigned short* Bt = Bbase + (size_t)bOffZ * z + (size_t)blockIdx.y * 256 * K;
  const float* bias = biasBase + (size_t)biasOffZ * z + blockIdx.y * 256;
  unsigned short* C = Cbase + (size_t)cOffZ * z + (size_t)blockIdx.x * 256 * ldc + blockIdx.y * 256;

  const int wave = tid >> 6, lane = tid & 63;
  const int wm = (wave >> 2) * 128, wn = (wave & 3) * 64;
  const int lm = lane & 15, lq = lane >> 4;
  const int sw = lm & 7;
  const int sr = tid >> 3;                               // staging row 0..63
  const int sc = (((tid & 7) ^ (sr & 7)) << 3);          // pre-swizzled source col
  const int NT = K >> 6;

  floatx4 acc[8][4] = {};
  short8 bf[4][2];                                       // B frags, live across a tile

  // Prologue: tile0 complete (4 half-tiles), pace, 3 half-tiles of tile1.
  STAGE_A256(0, 0, 0); STAGE_A256(0, 1, 0); STAGE_B256(0, 0, 0); STAGE_B256(0, 1, 0);
  asm volatile("s_waitcnt vmcnt(4)" ::: "memory");
  STAGE_B256(1, 0, 1); STAGE_A256(1, 0, 1); STAGE_B256(1, 1, 1);
  asm volatile("s_waitcnt vmcnt(6)" ::: "memory");
  __builtin_amdgcn_s_barrier();

  for (int t = 0; t < NT; ++t) {
    const int cur = t & 1;
    // p0 reads all B + A rows {0-31,128-159}; A-h2(t+1) region (cur^1) was
    // consumed by tile t-1 phases 2,3 (pre-boundary) -> safe.
    PHASE256(0, STAGE_A256(cur ^ 1, 1, t + 1), 0);
    // B fully consumed at p0 -> B halves of t+2 may land any time after.
    PHASE256(1, STAGE_B256(cur, 0, t + 2), 0);
    // A rows {0-63,128-191} consumed in p0,p1.
    PHASE256(2, STAGE_A256(cur, 0, t + 2), 0);
    // boundary: allow 3 half-tiles (6 loads) in flight -> tile t+1 landed.
    PHASE256(3, STAGE_B256(cur, 1, t + 2), 1);
  }

  asm volatile("s_waitcnt vmcnt(0)" ::: "memory");   // drain tail garbage stages

  float bv[4];
#pragma unroll
  for (int nj = 0; nj < 4; ++nj) bv[nj] = bias[wn + 16 * nj + lm];
#pragma unroll
  for (int mi = 0; mi < 8; ++mi) {
    const int row = wm + 16 * mi + lq * 4;
#pragma unroll
    for (int nj = 0; nj < 4; ++nj) {
      const int col = wn + 16 * nj + lm;
#pragma unroll
      for (int v = 0; v < 4; ++v) {
        float val = fmaxf(acc[mi][nj][v] + bv[nj], 0.0f);
        C[(size_t)(row + v) * ldc + col] = f32_to_bf16(val);
      }
    }
  }
}

// ---------------- combine: tic[t,bl,h] = sum_e gates[t,b0+bl,e] * eoc[bl,e,h] ----------------
__global__ void combine_kernel(const unsigned short* __restrict__ eo,
                               const float* __restrict__ gates,
                               unsigned short* __restrict__ ti,
                               int b0, int Bc) {
  int tid = blockIdx.x * 256 + threadIdx.x;
  int bl = tid >> 6;                 // chunk-local row
  int hc = (tid & 63) << 3;
  float g[3][8];
#pragma unroll
  for (int t = 0; t < 3; t++) {
    const floatx4* gp = (const floatx4*)(gates + ((size_t)t * 16384 + b0 + bl) * 8);
    floatx4 g0 = gp[0], g1 = gp[1];
#pragma unroll
    for (int j = 0; j < 4; j++) { g[t][j] = g0[j]; g[t][4 + j] = g1[j]; }
  }
  float out[3][8] = {};
#pragma unroll
  for (int e = 0; e < 8; e++) {
    ushortx8 v = *(const ushortx8*)(eo + ((size_t)bl * 8 + e) * 512 + hc);
#pragma unroll
    for (int j = 0; j < 8; j++) {
      float f = bf16_to_f32(v[j]);
#pragma unroll
      for (int t = 0; t < 3; t++) out[t][j] += g[t][e] * f;
    }
  }
#pragma unroll
  for (int t = 0; t < 3; t++) {
    ushortx8 o;
#pragma unroll
    for (int j = 0; j < 8; j++) o[j] = f32_to_bf16(out[t][j]);
    *(ushortx8*)(ti + ((size_t)t * Bc + bl) * 512 + hc) = o;
  }
}

// ---------------- fused towers: preds = sigmoid(relu(tic @ Wt1 + bt1) . Wt2 + bt2) ----------------
// 512 threads (8 waves), tile 128x256 (full tower width), K=512.
__global__ __launch_bounds__(512) void tower_fused_kernel(
    const unsigned short* __restrict__ tic, const unsigned short* __restrict__ Wt1T,
    const float* __restrict__ bt1, const float* __restrict__ Wt2,
    const float* __restrict__ bt2, float* __restrict__ out,
    int b0, int Bc) {
  __shared__ __align__(16) unsigned short As[128 * 64];   // 16 KB (reused for partials)
  __shared__ __align__(16) unsigned short Bs[256 * 64];   // 32 KB
  const int tid = threadIdx.x;
  const int mtiles = Bc >> 7;
  const int t = blockIdx.x / mtiles;            // task
  const int xbl = blockIdx.x % mtiles;          // m-tile within task
  const unsigned short* A = tic + ((size_t)t * Bc + (size_t)xbl * 128) * 512;
  const unsigned short* Bt = Wt1T + (size_t)t * 131072;

  const int wave = tid >> 6, lane = tid & 63;
  const int wm = (wave >> 2) * 64, wn = (wave & 3) * 64;
  const int lm = lane & 15, lq = lane >> 4;
  const int sw = lm & 7;

  floatx4 acc[4][4] = {};

  const int sr = tid >> 3;                               // staging row 0..63
  const int sc = (((tid & 7) ^ (sr & 7)) << 3);

  for (int kt = 0; kt < 512; kt += 64) {
#pragma unroll
    for (int i = 0; i < 2; i++)
      async_cp16(A + (size_t)(sr + 64 * i) * 512 + kt + sc,
                 (char*)As + i * 8192 + tid * 16);
#pragma unroll
    for (int i = 0; i < 4; i++)
      async_cp16(Bt + (size_t)(sr + 64 * i) * 512 + kt + sc,
                 (char*)Bs + i * 8192 + tid * 16);
    __syncthreads();
#pragma unroll
    for (int ks = 0; ks < 2; ks++) {
      short8 af[4], bf[4];
      const int ch = ((ks * 4 + lq) ^ sw) << 3;
#pragma unroll
      for (int i = 0; i < 4; i++)
        af[i] = *(const short8*)(As + (wm + 16 * i + lm) * 64 + ch);
#pragma unroll
      for (int j = 0; j < 4; j++)
        bf[j] = *(const short8*)(Bs + (wn + 16 * j + lm) * 64 + ch);
#pragma unroll
      for (int i = 0; i < 4; i++)
#pragma unroll
        for (int j = 0; j < 4; j++)
          acc[i][j] = __builtin_amdgcn_mfma_f32_16x16x32_bf16(af[i], bf[j], acc[i][j], 0, 0, 0);
    }
    __syncthreads();
  }

  // Epilogue: th = relu(acc + bt1[col]); partial[row] += th * Wt2[col]
  float b1v[4], w2v[4];
#pragma unroll
  for (int j = 0; j < 4; j++) {
    int col = wn + 16 * j + lm;
    b1v[j] = bt1[t * 256 + col];
    w2v[j] = Wt2[t * 256 + col];
  }
  float* pt = (float*)As;   // 128 rows x 4 wn-groups
#pragma unroll
  for (int i = 0; i < 4; i++) {
#pragma unroll
    for (int v = 0; v < 4; v++) {
      float p = 0.f;
#pragma unroll
      for (int j = 0; j < 4; j++)
        p += fmaxf(acc[i][j][v] + b1v[j], 0.0f) * w2v[j];
      p += __shfl_xor(p, 1, 64);
      p += __shfl_xor(p, 2, 64);
      p += __shfl_xor(p, 4, 64);
      p += __shfl_xor(p, 8, 64);
      if (lm == 0) pt[(wm + 16 * i + lq * 4 + v) * 4 + (wave & 3)] = p;
    }
  }
  __syncthreads();
  if (tid < 128) {
    float s = pt[tid * 4] + pt[tid * 4 + 1] + pt[tid * 4 + 2] + pt[tid * 4 + 3] + bt2[t];
    out[(t << 14) + b0 + xbl * 128 + tid] = 1.f / (1.f + __expf(-s));
  }
}

extern "C" void kernel_launch(void* const* d_in, const int* in_sizes, int n_in,
                              void* d_out, int out_size, void* d_ws, size_t ws_size,
                              hipStream_t stream) {
  (void)in_sizes; (void)n_in; (void)out_size;
  const float* x   = (const float*)d_in[0];
  const float* We1 = (const float*)d_in[1];
  const float* be1 = (const float*)d_in[2];
  const float* We2 = (const float*)d_in[3];
  const float* be2 = (const float*)d_in[4];
  const float* Wg  = (const float*)d_in[5];
  const float* bg  = (const float*)d_in[6];
  const float* Wt1 = (const float*)d_in[7];
  const float* bt1 = (const float*)d_in[8];
  const float* Wt2 = (const float*)d_in[9];
  const float* bt2 = (const float*)d_in[10];
  float* out = (float*)d_out;

  char* ws = (char*)d_ws;
  unsigned short* xb   = (unsigned short*)(ws + 0);            // 33,554,432
  unsigned short* W1T  = (unsigned short*)(ws + 33554432);     //  8,388,608
  unsigned short* W2T  = (unsigned short*)(ws + 41943040);     //  4,194,304
  unsigned short* Wt1T = (unsigned short*)(ws + 46137344);     //    786,432
  float*          gts  = (float*)(ws + 46923776);              //  1,572,864
  float*          WgT  = (float*)(ws + 48496640);              //     98,304
  const size_t fixed = 48594944;

  // Adaptive chunk size: per-chunk buffers need Bc*19456 bytes (h1c+eoc+tic).
  size_t rem = ws_size > fixed ? ws_size - fixed : 0;
  int Bc = 16384;
  while (Bc > 512 && (size_t)Bc * 19456 > rem) Bc >>= 1;
  const int nc = 16384 / Bc;

  char* cb = ws + fixed;
  unsigned short* h1c = (unsigned short*)(cb);                      // Bc*8192 B
  unsigned short* eoc = (unsigned short*)(cb + (size_t)Bc * 8192);  // Bc*8192 B
  unsigned short* tic = (unsigned short*)(cb + (size_t)Bc * 16384); // Bc*3072 B

  // --- prologue ---
  prep_kernel<<<dim3(16, 32, 20), dim3(32, 8), 0, stream>>>(We1, We2, Wt1, Wg, W1T, W2T, Wt1T, WgT);
  gates_cvt_kernel<<<4096, 256, 0, stream>>>(x, WgT, bg, gts, xb);

  // --- per-chunk pipeline ---
  for (int c = 0; c < nc; c++) {
    const unsigned short* xbc = xb + (size_t)c * Bc * 1024;
    if (Bc >= 4096) {
      // h1c = relu(x_chunk @ We1 + be1)   M=Bc N=512 K=1024 per expert
      gemm256_bt_relu<<<dim3(Bc / 256, 2, 8), 512, 0, stream>>>(
          xbc, 0L, 1024, W1T, 524288L, be1, 512, h1c, 512L, 4096, 1024);
      // eoc = relu(h1c @ We2 + be2)       M=Bc N=512 K=512 per expert
      gemm256_bt_relu<<<dim3(Bc / 256, 2, 8), 512, 0, stream>>>(
          h1c, 512L, 4096, W2T, 262144L, be2, 512, eoc, 512L, 4096, 512);
    } else {
      gemm_bt_relu<<<dim3(Bc / 128, 4, 8), 256, 0, stream>>>(
          xbc, 0L, 1024, W1T, 524288L, be1, 512, h1c, 512L, 4096, 1024);
      gemm_bt_relu<<<dim3(Bc / 128, 4, 8), 256, 0, stream>>>(
          h1c, 512L, 4096, W2T, 262144L, be2, 512, eoc, 512L, 4096, 512);
    }
    // tic[t,bl,:] = sum_e g * eoc
    combine_kernel<<<Bc / 4, 256, 0, stream>>>(eoc, gts, tic, c * Bc, Bc);
    // preds = sigmoid(relu(tic @ Wt1 + bt1) . Wt2 + bt2)
    tower_fused_kernel<<<3 * (Bc / 128), 512, 0, stream>>>(
        tic, Wt1T, bt1, Wt2, bt2, out, c * Bc, Bc);
  }
}

// Round 2
// 505.826 us; speedup vs baseline: 1.0281x; 1.0281x over previous
//
#include <hip/hip_runtime.h>

// MMoE: B=16384, D=1024, E=8, H=512, T=256, TASKS=3
// R2: 701 us. R3: 593 us (coalesced gates). R4: 521 us (XOR-swizzle LDS).
// R5: 498 us fuse tail; 10 launches.
// R6: 256x256 8-phase GEMM -> REGRESSED 520 us (gemm1 92.6us @ 30% MfmaUtil vs
//     128x128's 84us @ 37%). Diagnosis: reads distributed 12/4/4/4 with all
//     reads in the barrier-to-barrier gap where no MFMAs are in flight ->
//     LDS drain (up to 768 cyc) strictly serializes with MFMA (620 cyc) every
//     phase, + 8 barriers/tile.
// R7: v2 schedule for gemm1 only (gemm2 hedged back to proven 128x128):
//     - ks-split B reads (burst 12 -> 8), next-phase A reads issued inside
//       the current phase's MFMA window -> lgkm waits cover phase-old reads.
//     - single barrier per phase (4/tile, was 8). Race audit per region in
//       the phase comments below.
//
// Workspace: fixed 48,594,944 B + Bc*19456 B chunk buffers (Bc adapts).

#define BM 128
#define BN 128
#define BK 64

typedef __attribute__((ext_vector_type(8))) short short8;
typedef __attribute__((ext_vector_type(4))) float floatx4;
typedef __attribute__((ext_vector_type(4))) unsigned short ushortx4;
typedef __attribute__((ext_vector_type(8))) unsigned short ushortx8;

__device__ __forceinline__ unsigned short f32_to_bf16(float f) {
  unsigned int u = __float_as_uint(f);
  u += 0x7fffu + ((u >> 16) & 1u);   // round-to-nearest-even (no NaNs in this net)
  return (unsigned short)(u >> 16);
}
__device__ __forceinline__ float bf16_to_f32(unsigned short h) {
  return __uint_as_float(((unsigned int)h) << 16);
}

__device__ __forceinline__ void async_cp16(const void* g, void* lds) {
  __builtin_amdgcn_global_load_lds(
      (const __attribute__((address_space(1))) void*)g,
      (__attribute__((address_space(3))) void*)lds, 16, 0, 0);
}

// ---------------- all weight prep in one kernel ----------------
// grid (16,32,20), block (32,8):
//   z 0..7  : We1 slice z  [1024][512] -> W1T  [512][1024] bf16
//   z 8..15 : We2 slice    [512][512]  -> W2T  [512][512]  bf16 (y<16)
//   z 16..18: Wt1 slice    [512][256]  -> Wt1T [256][512]  bf16 (x<8,y<16)
//   z 19    : Wg [3][1024][8] -> WgT [3][8][1024] fp32      (x<16,y<6)
__device__ __forceinline__ void transpose_slice(
    const float* __restrict__ in, unsigned short* __restrict__ out,
    int K, int N, float (*tile)[33]) {
  int n0 = blockIdx.x * 32, k0 = blockIdx.y * 32;
  for (int i = threadIdx.y; i < 32; i += 8)
    tile[i][threadIdx.x] = in[(size_t)(k0 + i) * N + n0 + threadIdx.x];
  __syncthreads();
  for (int i = threadIdx.y; i < 32; i += 8)
    out[(size_t)(n0 + i) * K + k0 + threadIdx.x] = f32_to_bf16(tile[threadIdx.x][i]);
}

__global__ void prep_kernel(const float* __restrict__ We1, const float* __restrict__ We2,
                            const float* __restrict__ Wt1, const float* __restrict__ Wg,
                            unsigned short* __restrict__ W1T, unsigned short* __restrict__ W2T,
                            unsigned short* __restrict__ Wt1T, float* __restrict__ WgT) {
  __shared__ float tile[32][33];
  int z = blockIdx.z;
  if (z < 8) {
    transpose_slice(We1 + (size_t)z * 524288, W1T + (size_t)z * 524288, 1024, 512, tile);
  } else if (z < 16) {
    if (blockIdx.y < 16)
      transpose_slice(We2 + (size_t)(z - 8) * 262144, W2T + (size_t)(z - 8) * 262144, 512, 512, tile);
  } else if (z < 19) {
    if (blockIdx.x < 8 && blockIdx.y < 16)
      transpose_slice(Wt1 + (size_t)(z - 16) * 131072, Wt1T + (size_t)(z - 16) * 131072, 512, 256, tile);
  } else {
    if (blockIdx.x < 16 && blockIdx.y < 6) {
      int idx = (blockIdx.y * 16 + blockIdx.x) * 256 + threadIdx.y * 32 + threadIdx.x;
      int t = idx >> 13, r = idx & 8191, e = r >> 10, d = r & 1023;
      WgT[idx] = Wg[t * 8192 + d * 8 + e];
    }
  }
}

// ---------------- gates + x->bf16 (fused; reads x once) ----------------
// WgT: [3][8][1024] fp32. One wave per batch row.
__global__ __launch_bounds__(256) void gates_cvt_kernel(
    const float* __restrict__ x, const float* __restrict__ WgT,
    const float* __restrict__ bg, float* __restrict__ gout,
    unsigned short* __restrict__ xb) {
  int wave = threadIdx.x >> 6, lane = threadIdx.x & 63;
  int b = blockIdx.x * 4 + wave;
  const float* xr = x + (size_t)b * 1024;
  float xv[16];
#pragma unroll
  for (int j = 0; j < 16; j++) xv[j] = xr[lane + 64 * j];
  unsigned short* xbr = xb + (size_t)b * 1024;
#pragma unroll
  for (int j = 0; j < 16; j++) xbr[lane + 64 * j] = f32_to_bf16(xv[j]);
  float mylogit = 0.f;
#pragma unroll
  for (int te = 0; te < 24; te++) {
    const float* w = WgT + te * 1024;
    float a = 0.f;
#pragma unroll
    for (int j = 0; j < 16; j++) a += xv[j] * w[lane + 64 * j];
#pragma unroll
    for (int off = 32; off > 0; off >>= 1) a += __shfl_xor(a, off, 64);
    if (lane == te) mylogit = a;   // compile-time te -> cndmask, no LDS
  }
  if (lane < 24) {   // groups of 8 (tasks) are 8-lane aligned; xor 4/2/1 stays in-group
    int t = lane >> 3, e = lane & 7;
    float logit = mylogit + bg[lane];
    float m = logit;
    m = fmaxf(m, __shfl_xor(m, 4, 64));
    m = fmaxf(m, __shfl_xor(m, 2, 64));
    m = fmaxf(m, __shfl_xor(m, 1, 64));
    float ex = __expf(logit - m);
    float s = ex;
    s += __shfl_xor(s, 4, 64);
    s += __shfl_xor(s, 2, 64);
    s += __shfl_xor(s, 1, 64);
    gout[(size_t)t * 131072 + (size_t)b * 8 + e] = ex / s;
  }
}

// ---------------- m97-style 128x128 bf16 GEMM (proven; used for gemm2) ----------------
// C = relu(A * B^T + bias), bf16 out. LDS XOR-swizzled.
__global__ __launch_bounds__(256) void gemm_bt_relu(
    const unsigned short* __restrict__ Abase, long aOffZ, int lda,
    const unsigned short* __restrict__ Bbase, long bOffZ,
    const float* __restrict__ biasBase, int biasOffZ,
    unsigned short* __restrict__ Cbase, long cOffZ, int ldc,
    int K) {
  __shared__ __align__(16) unsigned short As[BM * BK];
  __shared__ __align__(16) unsigned short Bs[BN * BK];
  const int tid = threadIdx.x;
  const int z = blockIdx.z;
  const unsigned short* A = Abase + (size_t)aOffZ * z + (size_t)blockIdx.x * BM * lda;
  const unsigned short* Bt = Bbase + (size_t)bOffZ * z + (size_t)blockIdx.y * BN * K;
  const float* bias = biasBase + (size_t)biasOffZ * z + blockIdx.y * BN;
  unsigned short* C = Cbase + (size_t)cOffZ * z + (size_t)blockIdx.x * BM * ldc + blockIdx.y * BN;

  const int wave = tid >> 6, lane = tid & 63;
  const int wm = (wave >> 1) * 64, wn = (wave & 1) * 64;
  const int lm = lane & 15, lq = lane >> 4;
  const int sw = lm & 7;            // read-side swizzle key (= row & 7)

  floatx4 acc[4][4] = {};

  const int sr = tid >> 3;                               // staging row 0..31
  const int sc = (((tid & 7) ^ (sr & 7)) << 3);          // swizzled source col (elements)

  for (int kt = 0; kt < K; kt += BK) {
#pragma unroll
    for (int i = 0; i < 4; i++)
      async_cp16(A + (size_t)(sr + 32 * i) * lda + kt + sc,
                 (char*)As + i * 4096 + tid * 16);
#pragma unroll
    for (int i = 0; i < 4; i++)
      async_cp16(Bt + (size_t)(sr + 32 * i) * K + kt + sc,
                 (char*)Bs + i * 4096 + tid * 16);
    __syncthreads();   // drains vmcnt -> staged tiles visible
#pragma unroll
    for (int ks = 0; ks < 2; ks++) {
      short8 af[4], bf[4];
      const int ch = ((ks * 4 + lq) ^ sw) << 3;          // swizzled chunk (elements)
#pragma unroll
      for (int i = 0; i < 4; i++)
        af[i] = *(const short8*)(As + (wm + 16 * i + lm) * BK + ch);
#pragma unroll
      for (int j = 0; j < 4; j++)
        bf[j] = *(const short8*)(Bs + (wn + 16 * j + lm) * BK + ch);
#pragma unroll
      for (int i = 0; i < 4; i++)
#pragma unroll
        for (int j = 0; j < 4; j++)
          acc[i][j] = __builtin_amdgcn_mfma_f32_16x16x32_bf16(af[i], bf[j], acc[i][j], 0, 0, 0);
    }
    __syncthreads();   // protect LDS reuse next iter
  }

#pragma unroll
  for (int i = 0; i < 4; i++) {
    const int row = wm + 16 * i + lq * 4;
#pragma unroll
    for (int j = 0; j < 4; j++) {
      const int col = wn + 16 * j + lm;
      const float bv = bias[col];
#pragma unroll
      for (int v = 0; v < 4; v++) {
        float val = fmaxf(acc[i][j][v] + bv, 0.0f);
        C[(size_t)(row + v) * ldc + col] = f32_to_bf16(val);
      }
    }
  }
}

// ---------------- 256x256 4-phase counted-vmcnt GEMM, v2 schedule ----------------
// C = relu(A * B^T + bias), bf16 out. 512 threads = 8 waves (2M x 4N),
// per-wave 128x64. LDS 128 KiB: As[2][256][64] + Bs[2][256][64], chunk-XOR swz.
// Read plan per K-tile (24 ds_read_b128/wave): p0 issues af01+bf_ks0 (8), then
// bf_ks1+af23 (8) inside the MFMA window; p1/p2 issue af45/af67 early; every
// lgkm wait except p0's covers reads issued a full phase earlier.
// Staging (2-tile lookahead, A halves interleaved {0-63,128-191}/{64-127,192-255}):
//   p0: A-h1(t+1)->cur^1 | p1: B-h0(t+2)->cur | p2: A-h0(t+2)->cur | p3: B-h1(t+2)->cur
// Race audit (single barrier per phase): each stage's target region's last
// reader drains (lgkm before its MFMA cluster) strictly before that wave hits
// the phase-end barrier; the stage issues only after that barrier. Early reads
// are disjoint from same-phase stages (A-h0 vs A-h1, A vs B, or other buffer).
// Boundary: vmcnt(6) (3 half-tiles in flight) -> tile t+1 fully landed.

#define STAGE_A256(buf, half, tt) do {                                       \
    const int kt_ = ((tt) < NT ? (tt) : 0) << 6;                             \
    _Pragma("unroll") for (int g_ = 0; g_ < 2; ++g_) {                       \
      const int rb_ = ((half) + 2 * g_) * 64;                                \
      async_cp16(A + (size_t)(rb_ + sr) * lda + kt_ + sc,                    \
                 (char*)As + (buf) * 32768 + rb_ * 128 + tid * 16);          \
    } } while (0)

#define STAGE_B256(buf, half, tt) do {                                       \
    const int kt_ = ((tt) < NT ? (tt) : 0) << 6;                             \
    _Pragma("unroll") for (int g_ = 0; g_ < 2; ++g_) {                       \
      const int rb_ = (half) * 128 + g_ * 64;                                \
      async_cp16(Bt + (size_t)(rb_ + sr) * K + kt_ + sc,                     \
                 (char*)Bs + (buf) * 32768 + rb_ * 128 + tid * 16);          \
    } } while (0)

#define DS_A256(mi, ks)                                                      \
  (*(const short8*)(As + cur * 16384 + (wm + 16 * (mi) + lm) * 64 +          \
                    ((((ks) * 4 + lq) ^ sw) << 3)))
#define DS_B256(nj, ks)                                                      \
  (*(const short8*)(Bs + cur * 16384 + (wn + 16 * (nj) + lm) * 64 +          \
                    ((((ks) * 4 + lq) ^ sw) << 3)))

#define RD_A2(dst, mi0) do {                                                 \
    dst[0][0] = DS_A256((mi0), 0);     dst[0][1] = DS_A256((mi0), 1);        \
    dst[1][0] = DS_A256((mi0) + 1, 0); dst[1][1] = DS_A256((mi0) + 1, 1); } while (0)

#define WAIT_LGKM(n) do {                                                    \
    asm volatile("s_waitcnt lgkmcnt(" #n ")" ::: "memory");                  \
    __builtin_amdgcn_sched_barrier(0); } while (0)

// 16 MFMA: acc rows 2q,2q+1 from src (both ks)
#define MFMA16(src, q) do {                                                  \
    _Pragma("unroll") for (int d_ = 0; d_ < 2; ++d_)                         \
      _Pragma("unroll") for (int nj = 0; nj < 4; ++nj)                       \
        _Pragma("unroll") for (int ks = 0; ks < 2; ++ks)                     \
          acc[2 * (q) + d_][nj] = __builtin_amdgcn_mfma_f32_16x16x32_bf16(   \
              src[d_][ks], bfr[nj][ks], acc[2 * (q) + d_][nj], 0, 0, 0);     \
  } while (0)

__global__ __launch_bounds__(512) void gemm256_bt_relu(
    const unsigned short* __restrict__ Abase, long aOffZ, int lda,
    const unsigned short* __restrict__ Bbase, long bOffZ,
    const float* __restrict__ biasBase, int biasOffZ,
    unsigned short* __restrict__ Cbase, long cOffZ, int ldc,
    int K) {
  __shared__ __align__(16) unsigned short As[2 * 256 * 64];   // 64 KB
  __shared__ __align__(16) unsigned short Bs[2 * 256 * 64];   // 64 KB
  const int tid = threadIdx.x;
  const int z = blockIdx.z;
  const unsigned short* A = Abase + (size_t)aOffZ * z + (size_t)blockIdx.x * 256 * lda;
  const unsigned short* Bt = Bbase + (size_t)bOffZ * z + (size_t)blockIdx.y * 256 * K;
  const float* bias = biasBase + (size_t)biasOffZ * z + blockIdx.y * 256;
  unsigned short* C = Cbase + (size_t)cOffZ * z + (size_t)blockIdx.x * 256 * ldc + blockIdx.y * 256;

  const int wave = tid >> 6, lane = tid & 63;
  const int wm = (wave >> 2) * 128, wn = (wave & 3) * 64;
  const int lm = lane & 15, lq = lane >> 4;
  const int sw = lm & 7;
  const int sr = tid >> 3;                               // staging row 0..63
  const int sc = (((tid & 7) ^ (sr & 7)) << 3);          // pre-swizzled source col
  const int NT = K >> 6;

  floatx4 acc[8][4] = {};

  // Prologue: tile0 complete (4 half-tiles), pace, 3 half-tiles of tile1.
  // Steady-state invariant at each boundary: tile t+1 landed, 3 halves of
  // t+2 in flight (vmcnt 6).
  STAGE_A256(0, 0, 0); STAGE_A256(0, 1, 0); STAGE_B256(0, 0, 0); STAGE_B256(0, 1, 0);
  asm volatile("s_waitcnt vmcnt(4)" ::: "memory");
  STAGE_B256(1, 0, 1); STAGE_A256(1, 0, 1); STAGE_B256(1, 1, 1);
  asm volatile("s_waitcnt vmcnt(6)" ::: "memory");
  __builtin_amdgcn_s_barrier();

  for (int t = 0; t < NT; ++t) {
    const int cur = t & 1;
    short8 afA[2][2], afB[2][2], bfr[4][2];
    // ---- phase 0: acc[0..1], ks-split ----
    RD_A2(afA, 0);
    bfr[0][0] = DS_B256(0, 0); bfr[1][0] = DS_B256(1, 0);
    bfr[2][0] = DS_B256(2, 0); bfr[3][0] = DS_B256(3, 0);
    STAGE_A256(cur ^ 1, 1, t + 1);   // A-h1(t+1): its last readers (af45/af67
                                     // of t-1, same buffer) drained pre-boundary
    bfr[0][1] = DS_B256(0, 1); bfr[1][1] = DS_B256(1, 1);
    bfr[2][1] = DS_B256(2, 1); bfr[3][1] = DS_B256(3, 1);
    RD_A2(afB, 2);                   // early for p1
    WAIT_LGKM(8);                    // af01 + bf_ks0 done
    __builtin_amdgcn_s_setprio(1);
#pragma unroll
    for (int d_ = 0; d_ < 2; ++d_)
#pragma unroll
      for (int nj = 0; nj < 4; ++nj)
        acc[d_][nj] = __builtin_amdgcn_mfma_f32_16x16x32_bf16(
            afA[d_][0], bfr[nj][0], acc[d_][nj], 0, 0, 0);
    WAIT_LGKM(4);                    // bf_ks1 done (af23 may pend)
#pragma unroll
    for (int d_ = 0; d_ < 2; ++d_)
#pragma unroll
      for (int nj = 0; nj < 4; ++nj)
        acc[d_][nj] = __builtin_amdgcn_mfma_f32_16x16x32_bf16(
            afA[d_][1], bfr[nj][1], acc[d_][nj], 0, 0, 0);
    __builtin_amdgcn_s_setprio(0);
    __builtin_amdgcn_s_barrier();
    // ---- phase 1: acc[2..3] ----
    STAGE_B256(cur, 0, t + 2);       // B fully read in p0 (drained pre-barrier)
    RD_A2(afA, 4);                   // early for p2 (A-h1, disjoint from stages)
    WAIT_LGKM(4);                    // af23 done
    __builtin_amdgcn_s_setprio(1);
    MFMA16(afB, 1);
    __builtin_amdgcn_s_setprio(0);
    __builtin_amdgcn_s_barrier();
    // ---- phase 2: acc[4..5] ----
    STAGE_A256(cur, 0, t + 2);       // A-h0: af01/af23 drained pre-p1-barrier
    RD_A2(afB, 6);                   // early for p3 (A-h1 rows, disjoint)
    WAIT_LGKM(4);                    // af45 done
    __builtin_amdgcn_s_setprio(1);
    MFMA16(afA, 2);
    __builtin_amdgcn_s_setprio(0);
    __builtin_amdgcn_s_barrier();
    // ---- phase 3: acc[6..7] + boundary ----
    STAGE_B256(cur, 1, t + 2);
    WAIT_LGKM(0);                    // af67 done
    __builtin_amdgcn_s_setprio(1);
    MFMA16(afB, 3);
    __builtin_amdgcn_s_setprio(0);
    asm volatile("s_waitcnt vmcnt(6)" ::: "memory");   // tile t+1 landed
    __builtin_amdgcn_s_barrier();
  }

  asm volatile("s_waitcnt vmcnt(0)" ::: "memory");   // drain tail garbage stages

  float bv[4];
#pragma unroll
  for (int nj = 0; nj < 4; ++nj) bv[nj] = bias[wn + 16 * nj + lm];
#pragma unroll
  for (int mi = 0; mi < 8; ++mi) {
    const int row = wm + 16 * mi + lq * 4;
#pragma unroll
    for (int nj = 0; nj < 4; ++nj) {
      const int col = wn + 16 * nj + lm;
#pragma unroll
      for (int v = 0; v < 4; ++v) {
        float val = fmaxf(acc[mi][nj][v] + bv[nj], 0.0f);
        C[(size_t)(row + v) * ldc + col] = f32_to_bf16(val);
      }
    }
  }
}

// ---------------- combine: tic[t,bl,h] = sum_e gates[t,b0+bl,e] * eoc[bl,e,h] ----------------
__global__ void combine_kernel(const unsigned short* __restrict__ eo,
                               const float* __restrict__ gates,
                               unsigned short* __restrict__ ti,
                               int b0, int Bc) {
  int tid = blockIdx.x * 256 + threadIdx.x;
  int bl = tid >> 6;                 // chunk-local row
  int hc = (tid & 63) << 3;
  float g[3][8];
#pragma unroll
  for (int t = 0; t < 3; t++) {
    const floatx4* gp = (const floatx4*)(gates + ((size_t)t * 16384 + b0 + bl) * 8);
    floatx4 g0 = gp[0], g1 = gp[1];
#pragma unroll
    for (int j = 0; j < 4; j++) { g[t][j] = g0[j]; g[t][4 + j] = g1[j]; }
  }
  float out[3][8] = {};
#pragma unroll
  for (int e = 0; e < 8; e++) {
    ushortx8 v = *(const ushortx8*)(eo + ((size_t)bl * 8 + e) * 512 + hc);
#pragma unroll
    for (int j = 0; j < 8; j++) {
      float f = bf16_to_f32(v[j]);
#pragma unroll
      for (int t = 0; t < 3; t++) out[t][j] += g[t][e] * f;
    }
  }
#pragma unroll
  for (int t = 0; t < 3; t++) {
    ushortx8 o;
#pragma unroll
    for (int j = 0; j < 8; j++) o[j] = f32_to_bf16(out[t][j]);
    *(ushortx8*)(ti + ((size_t)t * Bc + bl) * 512 + hc) = o;
  }
}

// ---------------- fused towers: preds = sigmoid(relu(tic @ Wt1 + bt1) . Wt2 + bt2) ----------------
// 512 threads (8 waves), tile 128x256 (full tower width), K=512.
__global__ __launch_bounds__(512) void tower_fused_kernel(
    const unsigned short* __restrict__ tic, const unsigned short* __restrict__ Wt1T,
    const float* __restrict__ bt1, const float* __restrict__ Wt2,
    const float* __restrict__ bt2, float* __restrict__ out,
    int b0, int Bc) {
  __shared__ __align__(16) unsigned short As[128 * 64];   // 16 KB (reused for partials)
  __shared__ __align__(16) unsigned short Bs[256 * 64];   // 32 KB
  const int tid = threadIdx.x;
  const int mtiles = Bc >> 7;
  const int t = blockIdx.x / mtiles;            // task
  const int xbl = blockIdx.x % mtiles;          // m-tile within task
  const unsigned short* A = tic + ((size_t)t * Bc + (size_t)xbl * 128) * 512;
  const unsigned short* Bt = Wt1T + (size_t)t * 131072;

  const int wave = tid >> 6, lane = tid & 63;
  const int wm = (wave >> 2) * 64, wn = (wave & 3) * 64;
  const int lm = lane & 15, lq = lane >> 4;
  const int sw = lm & 7;

  floatx4 acc[4][4] = {};

  const int sr = tid >> 3;                               // staging row 0..63
  const int sc = (((tid & 7) ^ (sr & 7)) << 3);

  for (int kt = 0; kt < 512; kt += 64) {
#pragma unroll
    for (int i = 0; i < 2; i++)
      async_cp16(A + (size_t)(sr + 64 * i) * 512 + kt + sc,
                 (char*)As + i * 8192 + tid * 16);
#pragma unroll
    for (int i = 0; i < 4; i++)
      async_cp16(Bt + (size_t)(sr + 64 * i) * 512 + kt + sc,
                 (char*)Bs + i * 8192 + tid * 16);
    __syncthreads();
#pragma unroll
    for (int ks = 0; ks < 2; ks++) {
      short8 af[4], bf[4];
      const int ch = ((ks * 4 + lq) ^ sw) << 3;
#pragma unroll
      for (int i = 0; i < 4; i++)
        af[i] = *(const short8*)(As + (wm + 16 * i + lm) * 64 + ch);
#pragma unroll
      for (int j = 0; j < 4; j++)
        bf[j] = *(const short8*)(Bs + (wn + 16 * j + lm) * 64 + ch);
#pragma unroll
      for (int i = 0; i < 4; i++)
#pragma unroll
        for (int j = 0; j < 4; j++)
          acc[i][j] = __builtin_amdgcn_mfma_f32_16x16x32_bf16(af[i], bf[j], acc[i][j], 0, 0, 0);
    }
    __syncthreads();
  }

  // Epilogue: th = relu(acc + bt1[col]); partial[row] += th * Wt2[col]
  float b1v[4], w2v[4];
#pragma unroll
  for (int j = 0; j < 4; j++) {
    int col = wn + 16 * j + lm;
    b1v[j] = bt1[t * 256 + col];
    w2v[j] = Wt2[t * 256 + col];
  }
  float* pt = (float*)As;   // 128 rows x 4 wn-groups
#pragma unroll
  for (int i = 0; i < 4; i++) {
#pragma unroll
    for (int v = 0; v < 4; v++) {
      float p = 0.f;
#pragma unroll
      for (int j = 0; j < 4; j++)
        p += fmaxf(acc[i][j][v] + b1v[j], 0.0f) * w2v[j];
      p += __shfl_xor(p, 1, 64);
      p += __shfl_xor(p, 2, 64);
      p += __shfl_xor(p, 4, 64);
      p += __shfl_xor(p, 8, 64);
      if (lm == 0) pt[(wm + 16 * i + lq * 4 + v) * 4 + (wave & 3)] = p;
    }
  }
  __syncthreads();
  if (tid < 128) {
    float s = pt[tid * 4] + pt[tid * 4 + 1] + pt[tid * 4 + 2] + pt[tid * 4 + 3] + bt2[t];
    out[(t << 14) + b0 + xbl * 128 + tid] = 1.f / (1.f + __expf(-s));
  }
}

extern "C" void kernel_launch(void* const* d_in, const int* in_sizes, int n_in,
                              void* d_out, int out_size, void* d_ws, size_t ws_size,
                              hipStream_t stream) {
  (void)in_sizes; (void)n_in; (void)out_size;
  const float* x   = (const float*)d_in[0];
  const float* We1 = (const float*)d_in[1];
  const float* be1 = (const float*)d_in[2];
  const float* We2 = (const float*)d_in[3];
  const float* be2 = (const float*)d_in[4];
  const float* Wg  = (const float*)d_in[5];
  const float* bg  = (const float*)d_in[6];
  const float* Wt1 = (const float*)d_in[7];
  const float* bt1 = (const float*)d_in[8];
  const float* Wt2 = (const float*)d_in[9];
  const float* bt2 = (const float*)d_in[10];
  float* out = (float*)d_out;

  char* ws = (char*)d_ws;
  unsigned short* xb   = (unsigned short*)(ws + 0);            // 33,554,432
  unsigned short* W1T  = (unsigned short*)(ws + 33554432);     //  8,388,608
  unsigned short* W2T  = (unsigned short*)(ws + 41943040);     //  4,194,304
  unsigned short* Wt1T = (unsigned short*)(ws + 46137344);     //    786,432
  float*          gts  = (float*)(ws + 46923776);              //  1,572,864
  float*          WgT  = (float*)(ws + 48496640);              //     98,304
  const size_t fixed = 48594944;

  // Adaptive chunk size: per-chunk buffers need Bc*19456 bytes (h1c+eoc+tic).
  size_t rem = ws_size > fixed ? ws_size - fixed : 0;
  int Bc = 16384;
  while (Bc > 512 && (size_t)Bc * 19456 > rem) Bc >>= 1;
  const int nc = 16384 / Bc;

  char* cb = ws + fixed;
  unsigned short* h1c = (unsigned short*)(cb);                      // Bc*8192 B
  unsigned short* eoc = (unsigned short*)(cb + (size_t)Bc * 8192);  // Bc*8192 B
  unsigned short* tic = (unsigned short*)(cb + (size_t)Bc * 16384); // Bc*3072 B

  // --- prologue ---
  prep_kernel<<<dim3(16, 32, 20), dim3(32, 8), 0, stream>>>(We1, We2, Wt1, Wg, W1T, W2T, Wt1T, WgT);
  gates_cvt_kernel<<<4096, 256, 0, stream>>>(x, WgT, bg, gts, xb);

  // --- per-chunk pipeline ---
  for (int c = 0; c < nc; c++) {
    const unsigned short* xbc = xb + (size_t)c * Bc * 1024;
    if (Bc >= 4096) {
      // h1c = relu(x_chunk @ We1 + be1)   M=Bc N=512 K=1024 per expert (v2 schedule)
      gemm256_bt_relu<<<dim3(Bc / 256, 2, 8), 512, 0, stream>>>(
          xbc, 0L, 1024, W1T, 524288L, be1, 512, h1c, 512L, 4096, 1024);
    } else {
      gemm_bt_relu<<<dim3(Bc / 128, 4, 8), 256, 0, stream>>>(
          xbc, 0L, 1024, W1T, 524288L, be1, 512, h1c, 512L, 4096, 1024);
    }
    // eoc = relu(h1c @ We2 + be2)         M=Bc N=512 K=512 per expert (proven 128x128)
    gemm_bt_relu<<<dim3(Bc / 128, 4, 8), 256, 0, stream>>>(
        h1c, 512L, 4096, W2T, 262144L, be2, 512, eoc, 512L, 4096, 512);
    // tic[t,bl,:] = sum_e g * eoc
    combine_kernel<<<Bc / 4, 256, 0, stream>>>(eoc, gts, tic, c * Bc, Bc);
    // preds = sigmoid(relu(tic @ Wt1 + bt1) . Wt2 + bt2)
    tower_fused_kernel<<<3 * (Bc / 128), 512, 0, stream>>>(
        tic, Wt1T, bt1, Wt2, bt2, out, c * Bc, Bc);
  }
}